// Round 2
// baseline (898.434 us; speedup 1.0000x reference)
//
#include <hip/hip_runtime.h>
#include <hip/hip_bf16.h>

typedef __bf16 bf16x8 __attribute__((ext_vector_type(8)));
typedef float f32x4 __attribute__((ext_vector_type(4)));

#define MFMA16(a,b,c) __builtin_amdgcn_mfma_f32_16x16x32_bf16((a),(b),(c),0,0,0)

static constexpr int H_   = 256;
static constexpr int KEV  = 10;
static constexpr int NTOK = 32 * 4096;

// ---------- dtype-generic load/store helpers ----------
template<bool F32>
__device__ __forceinline__ float ldS(const void* p, size_t i){
    if constexpr (F32) return ((const float*)p)[i];
    else               return __bfloat162float(((const __hip_bfloat16*)p)[i]);
}

template<bool F32>
__device__ __forceinline__ bf16x8 ldFrag(const void* p, size_t off){
    if constexpr (F32){
        const float* q = (const float*)p + off;
        f32x4 a = *(const f32x4*)q;
        f32x4 b = *(const f32x4*)(q + 4);
        bf16x8 r;
        #pragma unroll
        for (int j = 0; j < 4; ++j){ r[j] = (__bf16)a[j]; r[4 + j] = (__bf16)b[j]; }
        return r;
    } else {
        return *(const bf16x8*)((const __hip_bfloat16*)p + off);
    }
}

template<bool F32>
__device__ __forceinline__ void stOut(void* p, size_t i, float v){
    if constexpr (F32) ((float*)p)[i] = v;
    else               ((__hip_bfloat16*)p)[i] = __float2bfloat16(v);
}

// tanh(x) = (e^{2x}-1)/(e^{2x}+1), clamped so e^{2x} never overflows; NaN-safe via clamp.
__device__ __forceinline__ float fast_tanh(float x){
    x = fminf(fmaxf(x, -9.0f), 9.0f);
    float e = __builtin_amdgcn_exp2f(2.8853900817779268f * x); // exp(2x)
    return (e - 1.0f) * __builtin_amdgcn_rcpf(e + 1.0f);
}

// ---------- dtype detection: b1 is 256 values in [eps,1] (all positive) ----------
// bf16: every uint16 has bit15 (sign) clear.  fp32: low halves are mantissa bits,
// bit15 ~ Bernoulli(1/2) over 128 low-halves -> P(all clear) = 2^-128.
__global__ void detect_kernel(const unsigned short* __restrict__ b1bits, int* __restrict__ flag){
    int lane = threadIdx.x;            // 64 threads
    unsigned short o = 0;
    #pragma unroll
    for (int i = 0; i < 4; ++i) o |= b1bits[lane * 4 + i];
    unsigned long long bal = __ballot((o & 0x8000) != 0);
    if (lane == 0) *flag = (bal != 0ull) ? 1 : 0;   // 1 = fp32, 0 = bf16
}

// v1[j] = sum_k w2[j][H+k]*w1[k];  c1[j] = sum_k w2[j][H+k]*b1[k] + b2[j]
template<bool F32>
__global__ void prep_kernel(const void* __restrict__ w1, const void* __restrict__ b1,
                            const void* __restrict__ w2, const void* __restrict__ b2,
                            float* __restrict__ vc, const int* __restrict__ flag){
    if (*flag != (F32 ? 1 : 0)) return;
    int j = threadIdx.x;
    size_t rowOff = (size_t)j * (2 * H_) + H_;
    float v = 0.f, cc = 0.f;
    #pragma unroll 8
    for (int k = 0; k < H_; ++k){
        float w = ldS<F32>(w2, rowOff + k);
        v  += w * ldS<F32>(w1, k);
        cc += w * ldS<F32>(b1, k);
    }
    vc[j]      = v;
    vc[H_ + j] = cc + ldS<F32>(b2, j);
}

template<bool F32>
__global__ __launch_bounds__(256, 2) void chfn_kernel(
    const void* __restrict__ hs,
    const void* __restrict__ td,
    const void* __restrict__ w2,
    const void* __restrict__ wA, const void* __restrict__ bA,
    const void* __restrict__ wB, const void* __restrict__ bB,
    const void* __restrict__ w3, const void* __restrict__ b3,
    const float* __restrict__ vc, const int* __restrict__ flag,
    void* __restrict__ out)
{
    if (*flag != (F32 ? 1 : 0)) return;

    // wave-private activation / tangent tiles, 16 tokens x 256 feats, chunk-swizzled.
    __shared__ alignas(16) __hip_bfloat16 sA[4 * 16 * H_];   // 32 KB
    __shared__ alignas(16) __hip_bfloat16 sD[4 * 16 * H_];   // 32 KB (64 KB total -> 2 blocks/CU)

    const int tid  = threadIdx.x;
    const int wave = tid >> 6;
    const int lane = tid & 63;
    const int q    = lane >> 4;   // quad 0..3
    const int c    = lane & 15;   // A/B row|col index, C/D col index
    const int tokenBase = blockIdx.x * 64 + wave * 16;
    const int wrow = wave * 16;

    // td for this wave's tokens; D rows are m = 4q + r
    float myTd = ldS<F32>(td, tokenBase + c);
    float tdv[4];
    #pragma unroll
    for (int r = 0; r < 4; ++r) tdv[r] = __shfl(myTd, q * 4 + r, 64);

    bf16x8 aF[8], aB[8];

    // ---------------- layer 1: out1 = tanh(h@w2h^T + td*v1 + c1), dout1 = (1-out1^2)*v1
    {
        size_t hrow = (size_t)(tokenBase + c) * H_ + 8 * q;
        #pragma unroll
        for (int s = 0; s < 8; ++s) aF[s] = ldFrag<F32>(hs, hrow + 32 * s);

        #pragma unroll 1
        for (int n0 = 0; n0 < 16; n0 += 2){
            f32x4 a0 = {0.f,0.f,0.f,0.f}, a1 = {0.f,0.f,0.f,0.f};
            size_t wp0 = (size_t)(n0 * 16 + c) * (2 * H_) + 8 * q;  // first 256 cols = w2_h
            size_t wp1 = wp0 + (size_t)16 * (2 * H_);
            #pragma unroll
            for (int s = 0; s < 8; ++s){
                bf16x8 b0v = ldFrag<F32>(w2, wp0 + 32 * s);
                bf16x8 b1v = ldFrag<F32>(w2, wp1 + 32 * s);
                a0 = MFMA16(aF[s], b0v, a0);
                a1 = MFMA16(aF[s], b1v, a1);
            }
            #pragma unroll
            for (int t = 0; t < 2; ++t){
                const f32x4& acc = t ? a1 : a0;
                int n = (n0 + t) * 16 + c;
                float v1n = vc[n], c1n = vc[H_ + n];
                #pragma unroll
                for (int r = 0; r < 4; ++r){
                    float x  = acc[r] + tdv[r] * v1n + c1n;
                    float th = fast_tanh(x);
                    float dd = (1.0f - th * th) * v1n;
                    int row = 4 * q + r;
                    int off = (wrow + row) * H_ + ((((n >> 3) + row) & 31) << 3) + (n & 7);
                    sA[off] = __float2bfloat16(th);
                    sD[off] = __float2bfloat16(dd);
                }
            }
        }
    }

    // ---------------- layers 2 & 3: out=tanh(act@W^T+b), dx=dact@W^T, dout=(1-out^2)*dx
    const void* Wmat[2] = {wA, wB};
    const void* bvec[2] = {bA, bB};
    #pragma unroll 1
    for (int L = 0; L < 2; ++L){
        const void* W    = Wmat[L];
        const void* bias = bvec[L];
        const __hip_bfloat16* arow = sA + (wrow + c) * H_;
        const __hip_bfloat16* drow = sD + (wrow + c) * H_;
        #pragma unroll
        for (int s = 0; s < 8; ++s){
            int ch = (((4 * s + q) + c) & 31) << 3;   // swizzled chunk
            aF[s] = *(const bf16x8*)(arow + ch);
            aB[s] = *(const bf16x8*)(drow + ch);
        }
        #pragma unroll 1
        for (int n0 = 0; n0 < 16; n0 += 2){
            f32x4 f0 = {0.f,0.f,0.f,0.f}, f1 = {0.f,0.f,0.f,0.f};
            f32x4 g0 = {0.f,0.f,0.f,0.f}, g1 = {0.f,0.f,0.f,0.f};
            size_t wp0 = (size_t)(n0 * 16 + c) * H_ + 8 * q;
            size_t wp1 = wp0 + (size_t)16 * H_;
            #pragma unroll
            for (int s = 0; s < 8; ++s){
                bf16x8 b0v = ldFrag<F32>(W, wp0 + 32 * s);
                bf16x8 b1v = ldFrag<F32>(W, wp1 + 32 * s);
                f0 = MFMA16(aF[s], b0v, f0);   // fwd, tile n0
                g0 = MFMA16(aB[s], b0v, g0);   // bwd, tile n0 (same weights!)
                f1 = MFMA16(aF[s], b1v, f1);   // fwd, tile n0+1
                g1 = MFMA16(aB[s], b1v, g1);   // bwd, tile n0+1
            }
            #pragma unroll
            for (int t = 0; t < 2; ++t){
                const f32x4& accf = t ? f1 : f0;
                const f32x4& accg = t ? g1 : g0;
                int n = (n0 + t) * 16 + c;
                float bn = ldS<F32>(bias, n);
                #pragma unroll
                for (int r = 0; r < 4; ++r){
                    float th = fast_tanh(accf[r] + bn);
                    float dd = (1.0f - th * th) * accg[r];
                    int row = 4 * q + r;
                    int off = (wrow + row) * H_ + ((((n >> 3) + row) & 31) << 3) + (n & 7);
                    sA[off] = __float2bfloat16(th);
                    sD[off] = __float2bfloat16(dd);
                }
            }
        }
    }

    // ---------------- layer 4 (head, K=10): z = out3@w3^T+b3, out = softplus(z), d = sigmoid(z)*dz/(B*S)
    {
        const __hip_bfloat16* arow = sA + (wrow + c) * H_;
        const __hip_bfloat16* drow = sD + (wrow + c) * H_;
        #pragma unroll
        for (int s = 0; s < 8; ++s){
            int ch = (((4 * s + q) + c) & 31) << 3;
            aF[s] = *(const bf16x8*)(arow + ch);
            aB[s] = *(const bf16x8*)(drow + ch);
        }
        int crow = (c < KEV) ? c : 0;   // clamp: no OOB; cols >=10 never stored
        size_t wp0 = (size_t)crow * H_ + 8 * q;
        f32x4 f0 = {0.f,0.f,0.f,0.f}, g0 = {0.f,0.f,0.f,0.f};
        #pragma unroll
        for (int s = 0; s < 8; ++s){
            bf16x8 b0v = ldFrag<F32>(w3, wp0 + 32 * s);
            f0 = MFMA16(aF[s], b0v, f0);
            g0 = MFMA16(aB[s], b0v, g0);
        }
        if (c < KEV){
            float bn = ldS<F32>(b3, c);
            #pragma unroll
            for (int r = 0; r < 4; ++r){
                float z  = f0[r] + bn;
                float a  = fabsf(z);
                float e  = __builtin_amdgcn_exp2f(-1.4426950408889634f * a); // exp(-|z|)
                float sp = fmaxf(z, 0.f) +
                           0.69314718055994531f * __builtin_amdgcn_logf(1.0f + e);
                float sg = __builtin_amdgcn_rcpf(1.0f + e);                  // 1/(1+e^{-|z|})
                sg = (z >= 0.f) ? sg : 1.0f - sg;                            // sigmoid(z)
                float dv = sg * g0[r] * (1.0f / 131072.0f);                  // /(B*S), exact pow2
                size_t token = tokenBase + 4 * q + r;
                stOut<F32>(out, token * KEV + c, sp);
                stOut<F32>(out, (size_t)NTOK * KEV + token * KEV + c, dv);
            }
        }
    }
}

extern "C" void kernel_launch(void* const* d_in, const int* in_sizes, int n_in,
                              void* d_out, int out_size, void* d_ws, size_t ws_size,
                              hipStream_t stream){
    const void* hs = d_in[0];
    const void* td = d_in[1];
    const void* w1 = d_in[2];
    const void* b1 = d_in[3];
    const void* w2 = d_in[4];
    const void* b2 = d_in[5];
    const void* wA = d_in[6];
    const void* bA = d_in[7];
    const void* wB = d_in[8];
    const void* bB = d_in[9];
    const void* w3 = d_in[10];
    const void* b3 = d_in[11];
    float* vc  = (float*)d_ws;                    // 512 floats: v1 | c1
    int*   flg = (int*)((char*)d_ws + 4096);      // dtype flag

    detect_kernel<<<1, 64, 0, stream>>>((const unsigned short*)b1, flg);
    prep_kernel<false><<<1, 256, 0, stream>>>(w1, b1, w2, b2, vc, flg);
    prep_kernel<true ><<<1, 256, 0, stream>>>(w1, b1, w2, b2, vc, flg);
    chfn_kernel<false><<<NTOK / 64, 256, 0, stream>>>(hs, td, w2, wA, bA, wB, bB, w3, b3, vc, flg, d_out);
    chfn_kernel<true ><<<NTOK / 64, 256, 0, stream>>>(hs, td, w2, wA, bA, wB, bB, w3, b3, vc, flg, d_out);
}

// Round 3
// 339.790 us; speedup vs baseline: 2.6441x; 2.6441x over previous
//
#include <hip/hip_runtime.h>
#include <hip/hip_bf16.h>
#include <stdint.h>

typedef __bf16 bf16x8 __attribute__((ext_vector_type(8)));
typedef float  f32x4  __attribute__((ext_vector_type(4)));

#define MFMA16(a,b,c) __builtin_amdgcn_mfma_f32_16x16x32_bf16((a),(b),(c),0,0,0)

static constexpr int H_   = 256;
static constexpr int KEV  = 10;
static constexpr int NTOK = 32 * 4096;
static constexpr int NCHUNK = 48;          // 3 layers x 16 chunks of 16 output rows

// tanh(x) = (e^{2x}-1)/(e^{2x}+1), clamped so e^{2x} never overflows; NaN-safe.
__device__ __forceinline__ float fast_tanh(float x){
    x = fminf(fmaxf(x, -9.0f), 9.0f);
    float e = __builtin_amdgcn_exp2f(2.8853900817779268f * x); // exp(2x)
    return (e - 1.0f) * __builtin_amdgcn_rcpf(e + 1.0f);
}

// async global->LDS 16B per lane: LDS dest is wave-uniform base + lane*16 (m104/m108)
__device__ __forceinline__ void cp16(void* lds, const void* g){
    auto l = reinterpret_cast<__attribute__((address_space(3))) uint32_t*>(
                 (uint32_t)reinterpret_cast<uintptr_t>(lds));
    auto s = reinterpret_cast<const __attribute__((address_space(1))) uint32_t*>(
                 reinterpret_cast<uintptr_t>(g));
    __builtin_amdgcn_global_load_lds(s, l, 16, 0, 0);
}

__device__ __forceinline__ bf16x8 cvtFrag(const float* p){
    f32x4 a = *(const f32x4*)p;
    f32x4 b = *(const f32x4*)(p + 4);
    bf16x8 r;
    #pragma unroll
    for (int j = 0; j < 4; ++j){ r[j] = (__bf16)a[j]; r[4 + j] = (__bf16)b[j]; }
    return r;
}

// ---- prep 1: v1[j] = sum_k w2[j][256+k]*w1[k]; c1[j] = sum_k w2[j][256+k]*b1[k] + b2[j]
__global__ void prep_vc(const float* __restrict__ w1, const float* __restrict__ b1,
                        const float* __restrict__ w2, const float* __restrict__ b2,
                        float* __restrict__ vc){
    int j = blockIdx.x * 4 + (threadIdx.x >> 6);   // 64 blocks x 4 waves = 256 rows
    int l = threadIdx.x & 63;
    const float* row = w2 + (size_t)j * (2 * H_) + H_;
    float v = 0.f, cc = 0.f;
    #pragma unroll
    for (int i = 0; i < 4; ++i){
        int k = l + 64 * i;
        float w = row[k];
        v  += w * w1[k];
        cc += w * b1[k];
    }
    #pragma unroll
    for (int off = 32; off; off >>= 1){
        v  += __shfl_down(v,  off, 64);
        cc += __shfl_down(cc, off, 64);
    }
    if (l == 0){ vc[j] = v; vc[H_ + j] = cc + b2[j]; }
}

// ---- prep 2: pack weights to bf16 in MFMA B-fragment order.
// chunk b (layer b>>4, n0 = b&15): slot = (s*4+q)*16+c holds W[n0*16+c][32s+8q .. +8]
__global__ void prep_pack(const float* __restrict__ w2, const float* __restrict__ wA,
                          const float* __restrict__ wB, __hip_bfloat16* __restrict__ pk){
    int b  = blockIdx.x;            // 48 chunks
    int L  = b >> 4, n0 = b & 15;
    const float* W = (L == 0) ? w2 : ((L == 1) ? wA : wB);
    int K = (L == 0) ? 2 * H_ : H_; // layer1 uses first 256 cols of w2 (the h part)
    __hip_bfloat16* dst = pk + (size_t)b * 4096;
    int t = threadIdx.x;
    #pragma unroll
    for (int u = 0; u < 2; ++u){
        int slot = t * 2 + u;                     // 0..511
        int s = slot >> 6, q = (slot >> 4) & 3, c = slot & 15;
        const float* src = W + (size_t)(n0 * 16 + c) * K + 32 * s + 8 * q;
        #pragma unroll
        for (int j = 0; j < 8; ++j) dst[slot * 8 + j] = __float2bfloat16(src[j]);
    }
}

__global__ __launch_bounds__(256, 2) void chfn_kernel(
    const float* __restrict__ hs, const float* __restrict__ td,
    const __hip_bfloat16* __restrict__ wpk,
    const float* __restrict__ bA, const float* __restrict__ bB,
    const float* __restrict__ w3, const float* __restrict__ b3,
    const float* __restrict__ vc,
    float* __restrict__ out)
{
    __shared__ __hip_bfloat16 sA[4 * 16 * H_];     // 32 KB activations
    __shared__ __hip_bfloat16 sD[4 * 16 * H_];     // 32 KB tangents
    __shared__ __hip_bfloat16 wls[2][4096];        // 2 x 8 KB weight-chunk ring

    const int tid  = threadIdx.x;
    const int wave = tid >> 6;
    const int lane = tid & 63;
    const int q    = lane >> 4;
    const int c    = lane & 15;
    const int tokenBase = blockIdx.x * 64 + wave * 16;
    const int wrow = wave * 16;

    // issue L1 A-fragment global loads early (fp32 hs, one-time per tile)
    const float* hrow = hs + (size_t)(tokenBase + c) * H_ + 8 * q;
    f32x4 h0[8], h1[8];
    #pragma unroll
    for (int s = 0; s < 8; ++s){
        h0[s] = *(const f32x4*)(hrow + 32 * s);
        h1[s] = *(const f32x4*)(hrow + 32 * s + 4);
    }

    // stage chunk 0 (8 KB): wave w copies KBs [2w, 2w+2)
    #pragma unroll
    for (int j = 0; j < 2; ++j){
        int i = wave * 2 + j;
        cp16((char*)&wls[0][0] + i * 1024, (const char*)wpk + i * 1024 + lane * 16);
    }

    float myTd = td[tokenBase + c];
    float tdv[4];
    #pragma unroll
    for (int r = 0; r < 4; ++r) tdv[r] = __shfl(myTd, q * 4 + r, 64);

    bf16x8 aF[8], aB[8];
    #pragma unroll
    for (int s = 0; s < 8; ++s){
        bf16x8 rr;
        #pragma unroll
        for (int j = 0; j < 4; ++j){ rr[j] = (__bf16)h0[s][j]; rr[4 + j] = (__bf16)h1[s][j]; }
        aF[s] = rr;
    }

    __syncthreads();   // chunk 0 staged

    int g = 0;
    // ---------------- layer 1: out1 = tanh(h@w2h^T + td*v1 + c1), dout1 = (1-out1^2)*v1
    #pragma unroll 1
    for (int n0 = 0; n0 < 16; ++n0, ++g){
        const __hip_bfloat16* cur = wls[g & 1];
        {   // prefetch next chunk into the other ring slot
            const char* src = (const char*)(wpk + (size_t)(g + 1) * 4096);
            #pragma unroll
            for (int j = 0; j < 2; ++j){
                int i = wave * 2 + j;
                cp16((char*)&wls[(g + 1) & 1][0] + i * 1024, src + i * 1024 + lane * 16);
            }
        }
        f32x4 f0 = {0.f,0.f,0.f,0.f};
        #pragma unroll
        for (int s = 0; s < 8; ++s){
            bf16x8 bv = *(const bf16x8*)(cur + ((s * 4 + q) * 16 + c) * 8);
            f0 = MFMA16(aF[s], bv, f0);
        }
        int n = n0 * 16 + c;
        float v1n = vc[n], c1n = vc[H_ + n];
        #pragma unroll
        for (int r = 0; r < 4; ++r){
            float x  = f0[r] + tdv[r] * v1n + c1n;
            float th = fast_tanh(x);
            float dd = (1.0f - th * th) * v1n;
            int row = 4 * q + r;
            int off = (wrow + row) * H_ + ((((n >> 3) + row) & 31) << 3) + (n & 7);
            sA[off] = __float2bfloat16(th);
            sD[off] = __float2bfloat16(dd);
        }
        __syncthreads();
    }

    // ---------------- layers 2 & 3: out=tanh(act@W^T+b), dx=dact@W^T, dout=(1-out^2)*dx
    const float* bias2[2] = {bA, bB};
    #pragma unroll 1
    for (int L = 0; L < 2; ++L){
        const float* bias = bias2[L];
        const __hip_bfloat16* arow = sA + (wrow + c) * H_;
        const __hip_bfloat16* drow = sD + (wrow + c) * H_;
        #pragma unroll
        for (int s = 0; s < 8; ++s){
            int ch = (((4 * s + q) + c) & 31) << 3;   // activation swizzle
            aF[s] = *(const bf16x8*)(arow + ch);
            aB[s] = *(const bf16x8*)(drow + ch);
        }
        #pragma unroll 1
        for (int n0 = 0; n0 < 16; ++n0, ++g){
            const __hip_bfloat16* cur = wls[g & 1];
            if (g + 1 < NCHUNK){
                const char* src = (const char*)(wpk + (size_t)(g + 1) * 4096);
                #pragma unroll
                for (int j = 0; j < 2; ++j){
                    int i = wave * 2 + j;
                    cp16((char*)&wls[(g + 1) & 1][0] + i * 1024, src + i * 1024 + lane * 16);
                }
            }
            f32x4 f0 = {0.f,0.f,0.f,0.f}, g0 = {0.f,0.f,0.f,0.f};
            #pragma unroll
            for (int s = 0; s < 8; ++s){
                bf16x8 bv = *(const bf16x8*)(cur + ((s * 4 + q) * 16 + c) * 8);
                f0 = MFMA16(aF[s], bv, f0);   // fwd
                g0 = MFMA16(aB[s], bv, g0);   // tangent (same weights)
            }
            int n = n0 * 16 + c;
            float bn = bias[n];
            #pragma unroll
            for (int r = 0; r < 4; ++r){
                float th = fast_tanh(f0[r] + bn);
                float dd = (1.0f - th * th) * g0[r];
                int row = 4 * q + r;
                int off = (wrow + row) * H_ + ((((n >> 3) + row) & 31) << 3) + (n & 7);
                sA[off] = __float2bfloat16(th);
                sD[off] = __float2bfloat16(dd);
            }
            __syncthreads();
        }
    }

    // ---------------- head (K=10): z = out3@w3^T+b3 -> softplus / sigmoid*dz/(B*S)
    {
        const __hip_bfloat16* arow = sA + (wrow + c) * H_;
        const __hip_bfloat16* drow = sD + (wrow + c) * H_;
        #pragma unroll
        for (int s = 0; s < 8; ++s){
            int ch = (((4 * s + q) + c) & 31) << 3;
            aF[s] = *(const bf16x8*)(arow + ch);
            aB[s] = *(const bf16x8*)(drow + ch);
        }
        int crow = (c < KEV) ? c : 0;   // clamp: no OOB; cols >=10 never stored
        const float* wp0 = w3 + (size_t)crow * H_ + 8 * q;
        f32x4 f0 = {0.f,0.f,0.f,0.f}, g0 = {0.f,0.f,0.f,0.f};
        #pragma unroll
        for (int s = 0; s < 8; ++s){
            bf16x8 bv = cvtFrag(wp0 + 32 * s);
            f0 = MFMA16(aF[s], bv, f0);
            g0 = MFMA16(aB[s], bv, g0);
        }
        if (c < KEV){
            float bn = b3[c];
            #pragma unroll
            for (int r = 0; r < 4; ++r){
                float z  = f0[r] + bn;
                float a  = fabsf(z);
                float e  = __builtin_amdgcn_exp2f(-1.4426950408889634f * a); // exp(-|z|)
                float sp = fmaxf(z, 0.f) +
                           0.69314718055994531f * __builtin_amdgcn_logf(1.0f + e);
                float sg = __builtin_amdgcn_rcpf(1.0f + e);                  // 1/(1+e^{-|z|})
                sg = (z >= 0.f) ? sg : 1.0f - sg;                            // sigmoid(z)
                float dv = sg * g0[r] * (1.0f / 131072.0f);                  // /(B*S)
                size_t token = tokenBase + 4 * q + r;
                out[token * KEV + c] = sp;
                out[(size_t)NTOK * KEV + token * KEV + c] = dv;
            }
        }
    }
}

extern "C" void kernel_launch(void* const* d_in, const int* in_sizes, int n_in,
                              void* d_out, int out_size, void* d_ws, size_t ws_size,
                              hipStream_t stream){
    const float* hs = (const float*)d_in[0];
    const float* td = (const float*)d_in[1];
    const float* w1 = (const float*)d_in[2];
    const float* b1 = (const float*)d_in[3];
    const float* w2 = (const float*)d_in[4];
    const float* b2 = (const float*)d_in[5];
    const float* wA = (const float*)d_in[6];
    const float* bA = (const float*)d_in[7];
    const float* wB = (const float*)d_in[8];
    const float* bB = (const float*)d_in[9];
    const float* w3 = (const float*)d_in[10];
    const float* b3 = (const float*)d_in[11];

    float*          vc  = (float*)d_ws;                              // 512 fp32
    __hip_bfloat16* wpk = (__hip_bfloat16*)((char*)d_ws + 4096);     // 48*4096 bf16 = 384 KB
    float*          outp = (float*)d_out;

    prep_vc  <<<64, 256, 0, stream>>>(w1, b1, w2, b2, vc);
    prep_pack<<<48, 256, 0, stream>>>(w2, wA, wB, wpk);
    chfn_kernel<<<NTOK / 64, 256, 0, stream>>>(hs, td, wpk, bA, bB, w3, b3, vc, outp);
}